// Round 1
// baseline (361.676 us; speedup 1.0000x reference)
//
#include <hip/hip_runtime.h>
#include <math.h>

// Problem constants (from reference): B=64, T=4096, H=256, all fp32.
constexpr int B_ = 64;
constexpr int T_ = 4096;
constexpr int H_ = 256;

constexpr int CHUNKS = 8;                       // T-chunks per batch row
constexpr int ROWS_PER_CHUNK = T_ / CHUNKS;     // 512
constexpr int WAVES = 4;                        // 256-thread block = 4 waves
constexpr int ROWS_PER_WAVE = ROWS_PER_CHUNK / WAVES;  // 128
constexpr int NBLK = B_ * CHUNKS;               // 512 blocks = 2 blocks/CU

// Fused pass: scores + online softmax + weighted accumulation, single HBM read
// of token_embeddings. Each wave: 128 rows; lane l holds columns [4l, 4l+4).
__global__ __launch_bounds__(256) void pool_pass1(
    const float* __restrict__ emb, const float* __restrict__ mask,
    const float* __restrict__ query, float* __restrict__ ws_acc,
    float* __restrict__ ws_m, float* __restrict__ ws_l)
{
    const int blk  = blockIdx.x;
    const int b    = blk >> 3;          // / CHUNKS
    const int c    = blk & (CHUNKS - 1);
    const int wave = threadIdx.x >> 6;
    const int lane = threadIdx.x & 63;

    const float4 q = ((const float4*)query)[lane];
    const int row0 = c * ROWS_PER_CHUNK + wave * ROWS_PER_WAVE;
    const float4* src  = (const float4*)emb + (size_t)(b * T_ + row0) * (H_ / 4) + lane;
    const float*  mrow = mask + (size_t)b * T_ + row0;

    // Online-softmax state. Sentinel -1e30 (not -inf) keeps exp(m - m_new)
    // finite even before any unmasked row is seen.
    float  m = -1e30f, l = 0.f;
    float4 acc = make_float4(0.f, 0.f, 0.f, 0.f);

    for (int r = 0; r < ROWS_PER_WAVE; r += 4) {
        // 4 independent 1KB/wave coalesced row loads (latency hiding + ILP)
        float4 v0 = src[(size_t)(r + 0) * 64];
        float4 v1 = src[(size_t)(r + 1) * 64];
        float4 v2 = src[(size_t)(r + 2) * 64];
        float4 v3 = src[(size_t)(r + 3) * 64];

        float s0 = v0.x * q.x + v0.y * q.y + v0.z * q.z + v0.w * q.w;
        float s1 = v1.x * q.x + v1.y * q.y + v1.z * q.z + v1.w * q.w;
        float s2 = v2.x * q.x + v2.y * q.y + v2.z * q.z + v2.w * q.w;
        float s3 = v3.x * q.x + v3.y * q.y + v3.z * q.z + v3.w * q.w;

        // wave64 allreduce, 4 interleaved chains
        #pragma unroll
        for (int off = 32; off; off >>= 1) {
            s0 += __shfl_xor(s0, off, 64);
            s1 += __shfl_xor(s1, off, 64);
            s2 += __shfl_xor(s2, off, 64);
            s3 += __shfl_xor(s3, off, 64);
        }

        // mask==0 -> -inf  (exp gives exact 0 below)
        if (mrow[r + 0] == 0.f) s0 = -INFINITY;
        if (mrow[r + 1] == 0.f) s1 = -INFINITY;
        if (mrow[r + 2] == 0.f) s2 = -INFINITY;
        if (mrow[r + 3] == 0.f) s3 = -INFINITY;

        const float m_new = fmaxf(fmaxf(fmaxf(s0, s1), fmaxf(s2, s3)), m);
        const float scale = __expf(m - m_new);
        const float p0 = __expf(s0 - m_new);
        const float p1 = __expf(s1 - m_new);
        const float p2 = __expf(s2 - m_new);
        const float p3 = __expf(s3 - m_new);

        l = l * scale + (p0 + p1) + (p2 + p3);
        acc.x = acc.x * scale + p0 * v0.x + p1 * v1.x + p2 * v2.x + p3 * v3.x;
        acc.y = acc.y * scale + p0 * v0.y + p1 * v1.y + p2 * v2.y + p3 * v3.y;
        acc.z = acc.z * scale + p0 * v0.z + p1 * v1.z + p2 * v2.z + p3 * v3.z;
        acc.w = acc.w * scale + p0 * v0.w + p1 * v1.w + p2 * v2.w + p3 * v3.w;
        m = m_new;
    }

    // Intra-block merge of the 4 wave states via LDS.
    __shared__ float sm[WAVES];
    __shared__ float sl[WAVES];
    __shared__ float sacc[WAVES][H_];
    if (lane == 0) { sm[wave] = m; sl[wave] = l; }
    ((float4*)&sacc[wave][0])[lane] = acc;   // columns 4*lane..4*lane+3
    __syncthreads();

    const float M  = fmaxf(fmaxf(sm[0], sm[1]), fmaxf(sm[2], sm[3]));
    const float w0 = __expf(sm[0] - M);
    const float w1 = __expf(sm[1] - M);
    const float w2 = __expf(sm[2] - M);
    const float w3 = __expf(sm[3] - M);
    const int t = threadIdx.x;               // thread t owns column t
    const float num = w0 * sacc[0][t] + w1 * sacc[1][t]
                    + w2 * sacc[2][t] + w3 * sacc[3][t];
    ws_acc[(size_t)blk * H_ + t] = num;
    if (t == 0) {
        ws_m[blk] = M;
        ws_l[blk] = w0 * sl[0] + w1 * sl[1] + w2 * sl[2] + w3 * sl[3];
    }
}

// Cross-chunk merge: one block per batch row, thread t owns column t.
__global__ __launch_bounds__(256) void pool_merge(
    const float* __restrict__ ws_acc, const float* __restrict__ ws_m,
    const float* __restrict__ ws_l, float* __restrict__ out)
{
    const int b = blockIdx.x;
    const int t = threadIdx.x;

    float M = -1e30f;
    #pragma unroll
    for (int c = 0; c < CHUNKS; ++c) M = fmaxf(M, ws_m[b * CHUNKS + c]);

    float den = 0.f, num = 0.f;
    #pragma unroll
    for (int c = 0; c < CHUNKS; ++c) {
        const float w = __expf(ws_m[b * CHUNKS + c] - M);
        den += w * ws_l[b * CHUNKS + c];
        num += w * ws_acc[(size_t)(b * CHUNKS + c) * H_ + t];
    }
    out[b * H_ + t] = num / den;
}

extern "C" void kernel_launch(void* const* d_in, const int* in_sizes, int n_in,
                              void* d_out, int out_size, void* d_ws, size_t ws_size,
                              hipStream_t stream) {
    const float* emb   = (const float*)d_in[0];  // [B,T,H] fp32
    const float* mask  = (const float*)d_in[1];  // [B,T]   fp32
    const float* query = (const float*)d_in[2];  // [H]     fp32
    float* out = (float*)d_out;                  // [B,H]   fp32

    // Workspace layout: acc[NBLK*H] | m[NBLK] | l[NBLK]  (~528 KB)
    float* ws_acc = (float*)d_ws;
    float* ws_m   = ws_acc + (size_t)NBLK * H_;
    float* ws_l   = ws_m + NBLK;

    pool_pass1<<<NBLK, 256, 0, stream>>>(emb, mask, query, ws_acc, ws_m, ws_l);
    pool_merge<<<B_, 256, 0, stream>>>(ws_acc, ws_m, ws_l, out);
}